// Round 4
// baseline (290.447 us; speedup 1.0000x reference)
//
#include <hip/hip_runtime.h>
#include <hip/hip_bf16.h>

#define NN 10000
#define NE 160000
#define NET 170000   // edges + self loops
#define IN_DIM 512
#define D1 1024      // HEADS*HID
#define HEADS 4
#define HID 256
#define OUT_DIM 512
#define NEG_SLOPE 0.2f

typedef __attribute__((ext_vector_type(8))) short bf16x8;
typedef __attribute__((ext_vector_type(4))) float f32x4;

__device__ inline float b2f(unsigned short b) {
    union { unsigned u; float f; } x; x.u = ((unsigned)b) << 16; return x.f;
}
__device__ inline unsigned short f2b(float f) {
    union { float f; unsigned u; } x; x.f = f;
    unsigned u = x.u;
    unsigned r = u + 0x7FFFu + ((u >> 16) & 1u);
    return (unsigned short)(r >> 16);
}
__device__ inline float lrelu(float v) { return v > 0.f ? v : NEG_SLOPE * v; }

// ---- init: zero counts/cursor + aS/aD (for fused att atomics); block 0 detects
// edge_index dtype (int64 -> high words of first 500 values are all 0)
__global__ void init_kernel(const int* ei32, int* flag, int* counts, int* cursor,
                            float* aS, float* aD) {
    int i = blockIdx.x * blockDim.x + threadIdx.x;
    if (i < NN) { counts[i] = 0; cursor[i] = 0; }
    for (int k = i; k < NN * HEADS; k += 40 * 256) { aS[k] = 0.f; aD[k] = 0.f; }
    if (blockIdx.x == 0) {
        __shared__ int nz;
        if (threadIdx.x == 0) nz = 0;
        __syncthreads();
        int acc = 0;
        for (int k = threadIdx.x; k < 500; k += 256) acc |= ei32[2 * k + 1];
        if (acc) atomicOr(&nz, 1);
        __syncthreads();
        if (threadIdx.x == 0) flag[0] = (nz == 0) ? 1 : 0;
    }
}

__global__ void zatt_kernel(float* aS, float* aD) {
    int i = blockIdx.x * blockDim.x + threadIdx.x;
    if (i < NN * HEADS) { aS[i] = 0.f; aD[i] = 0.f; }
}

__device__ inline void load_edge(const void* ei, int f64, int e, int& s, int& d) {
    if (f64) {
        const long long* p = (const long long*)ei;
        s = (int)p[e]; d = (int)p[NE + e];
    } else {
        const int* p = (const int*)ei;
        s = p[e]; d = p[NE + e];
    }
}

__global__ void count_kernel(const void* ei, const int* flag, int* counts) {
    int e = blockIdx.x * blockDim.x + threadIdx.x;
    if (e >= NET) return;
    int s, d;
    if (e < NE) load_edge(ei, *flag, e, s, d);
    else d = e - NE;
    atomicAdd(&counts[d], 1);
}

__global__ __launch_bounds__(256) void scan_kernel(const int* counts, int* indptr) {
    __shared__ int part[256];
    int t = threadIdx.x;
    int base = t * 40;
    int local[40];
    int sum = 0;
#pragma unroll
    for (int k = 0; k < 40; k++) {
        int i = base + k;
        int c = (i < NN) ? counts[i] : 0;
        local[k] = sum;
        sum += c;
    }
    part[t] = sum;
    __syncthreads();
    for (int off = 1; off < 256; off <<= 1) {
        int v = (t >= off) ? part[t - off] : 0;
        __syncthreads();
        part[t] += v;
        __syncthreads();
    }
    int excl = part[t] - sum;
#pragma unroll
    for (int k = 0; k < 40; k++) {
        int i = base + k;
        if (i < NN) indptr[i] = excl + local[k];
    }
    if (t == 255) indptr[NN] = part[255];
}

__global__ void fill_kernel(const void* ei, const int* flag, const int* indptr,
                            int* cursor, int* csr_src) {
    int e = blockIdx.x * blockDim.x + threadIdx.x;
    if (e >= NET) return;
    int s, d;
    if (e < NE) load_edge(ei, *flag, e, s, d);
    else { s = e - NE; d = s; }
    int pos = indptr[d] + atomicAdd(&cursor[d], 1);
    csr_src[pos] = s;
}

// ---- prep: fused x->bf16 convert + 3 weight transposes (sectioned 1D grid)
__device__ void tpose_tile(const float* __restrict__ in, unsigned short* __restrict__ out,
                           int R, int C, int bx, int by) {
    __shared__ float tile[32][33];
    int tx = threadIdx.x & 31, ty = threadIdx.x >> 5;
    int c = bx * 32 + tx;
#pragma unroll
    for (int r0 = 0; r0 < 32; r0 += 8) {
        int r = by * 32 + ty + r0;
        tile[ty + r0][tx] = in[(size_t)r * C + c];
    }
    __syncthreads();
    int oc = by * 32 + tx;
#pragma unroll
    for (int r0 = 0; r0 < 32; r0 += 8) {
        int orow = bx * 32 + ty + r0;
        out[(size_t)orow * R + oc] = f2b(tile[tx][ty + r0]);
    }
}

#define CVT_NB 5000   // NN*IN_DIM/4/256
#define TP1_NB 512    // (D1/32)*(IN_DIM/32)
#define TP2_NB 1024   // (D1/32)*(D1/32)
#define TP3_NB 512    // (OUT_DIM/32)*(D1/32)
__global__ __launch_bounds__(256) void prep_kernel(
    const float* __restrict__ x, unsigned short* __restrict__ xb,
    const float* __restrict__ W1, unsigned short* __restrict__ W1t,
    const float* __restrict__ W2, unsigned short* __restrict__ W2t,
    const float* __restrict__ fcW, unsigned short* __restrict__ fcWt) {
    int b = blockIdx.x;
    if (b < CVT_NB) {
        int i = b * 256 + threadIdx.x;
        float4 v = reinterpret_cast<const float4*>(x)[i];
        ushort4 o;
        o.x = f2b(v.x); o.y = f2b(v.y); o.z = f2b(v.z); o.w = f2b(v.w);
        reinterpret_cast<ushort4*>(xb)[i] = o;
        return;
    }
    b -= CVT_NB;
    if (b < TP1_NB) { tpose_tile(W1, W1t, IN_DIM, D1, b & 31, b >> 5); return; }
    b -= TP1_NB;
    if (b < TP2_NB) { tpose_tile(W2, W2t, D1, D1, b & 31, b >> 5); return; }
    b -= TP2_NB;
    tpose_tile(fcW, fcWt, D1, OUT_DIM, b & 15, b >> 4);
}

// ---- C[M][N] = A[M][K](bf16) @ B[N][K](bf16)^T ; m97 structure + optional
// fused attention-dot epilogue (aS/aD partials via 16-lane reduce + atomicAdd).
#define BM 128
#define BN 128
#define BK 32
__global__ __launch_bounds__(256) void gemm128(
    const unsigned short* __restrict__ A, const unsigned short* __restrict__ B,
    const float* __restrict__ bias, float* __restrict__ Cf, unsigned short* __restrict__ Cb,
    const float* __restrict__ attS, const float* __restrict__ attD,
    float* __restrict__ aSo, float* __restrict__ aDo,
    int M, int N, int K) {
    __shared__ __align__(16) unsigned short As[BM * BK];  // 8 KB linear [128][32]
    __shared__ __align__(16) unsigned short Bs[BN * BK];  // 8 KB
    int t = threadIdx.x;
    int row0 = blockIdx.x * BM, col0 = blockIdx.y * BN;
    int w = t >> 6, l = t & 63;
    int wr = w >> 1, wc = w & 1;
    f32x4 acc[4][4] = {};

    int sr = t >> 2;              // 0..63 (row within half-tile)
    int sc = (t & 3) * 8;         // k offset in shorts
    int arow0 = min(row0 + sr, M - 1);        // clamp: dup rows only feed guarded outputs
    int arow1 = min(row0 + 64 + sr, M - 1);
    const unsigned short* aptr0 = A + (size_t)arow0 * K + sc;
    const unsigned short* aptr1 = A + (size_t)arow1 * K + sc;
    const unsigned short* bptr0 = B + (size_t)(col0 + sr) * K + sc;
    const unsigned short* bptr1 = B + (size_t)(col0 + 64 + sr) * K + sc;
    unsigned short* asd0 = As + w * 512;          // wave-uniform LDS dests
    unsigned short* asd1 = As + 2048 + w * 512;
    unsigned short* bsd0 = Bs + w * 512;
    unsigned short* bsd1 = Bs + 2048 + w * 512;

    int rr = l & 15;
    int kk = (l >> 4) * 8;

    for (int k0 = 0; k0 < K; k0 += BK) {
        __builtin_amdgcn_global_load_lds(
            (const __attribute__((address_space(1))) void*)(aptr0 + k0),
            (__attribute__((address_space(3))) void*)asd0, 16, 0, 0);
        __builtin_amdgcn_global_load_lds(
            (const __attribute__((address_space(1))) void*)(aptr1 + k0),
            (__attribute__((address_space(3))) void*)asd1, 16, 0, 0);
        __builtin_amdgcn_global_load_lds(
            (const __attribute__((address_space(1))) void*)(bptr0 + k0),
            (__attribute__((address_space(3))) void*)bsd0, 16, 0, 0);
        __builtin_amdgcn_global_load_lds(
            (const __attribute__((address_space(1))) void*)(bptr1 + k0),
            (__attribute__((address_space(3))) void*)bsd1, 16, 0, 0);
        __syncthreads();

        bf16x8 af[4], bfv[4];
#pragma unroll
        for (int mi = 0; mi < 4; mi++)
            af[mi] = *reinterpret_cast<const bf16x8*>(&As[(wr * 64 + mi * 16 + rr) * BK + kk]);
#pragma unroll
        for (int ni = 0; ni < 4; ni++)
            bfv[ni] = *reinterpret_cast<const bf16x8*>(&Bs[(wc * 64 + ni * 16 + rr) * BK + kk]);
#pragma unroll
        for (int mi = 0; mi < 4; mi++)
#pragma unroll
            for (int ni = 0; ni < 4; ni++)
                acc[mi][ni] = __builtin_amdgcn_mfma_f32_16x16x32_bf16(af[mi], bfv[ni], acc[mi][ni], 0, 0, 0);
        __syncthreads();
    }

    // C/D: col = lane&15, row = (lane>>4)*4 + j
    int c_l = l & 15, r_h = (l >> 4) * 4;
#pragma unroll
    for (int mi = 0; mi < 4; mi++)
#pragma unroll
        for (int ni = 0; ni < 4; ni++) {
            int gc = col0 + wc * 64 + ni * 16 + c_l;
#pragma unroll
            for (int j = 0; j < 4; j++) {
                int gr = row0 + wr * 64 + mi * 16 + r_h + j;
                if (gr < M) {
                    float v = acc[mi][ni][j];
                    if (bias) v += bias[gc];
                    if (Cf) Cf[(size_t)gr * N + gc] = v;
                    if (Cb) Cb[(size_t)gr * N + gc] = f2b(v);
                }
            }
        }

    // fused attention partial dots: block's 128 cols lie in ONE head (col0>>8)
    if (attS) {
        int head = col0 >> 8;
        int cbase = (col0 & 255) + wc * 64 + c_l;
        float asv0 = attS[head * HID + cbase];
        float asv1 = attS[head * HID + cbase + 16];
        float asv2 = attS[head * HID + cbase + 32];
        float asv3 = attS[head * HID + cbase + 48];
        float adv0 = attD[head * HID + cbase];
        float adv1 = attD[head * HID + cbase + 16];
        float adv2 = attD[head * HID + cbase + 32];
        float adv3 = attD[head * HID + cbase + 48];
#pragma unroll
        for (int mi = 0; mi < 4; mi++)
#pragma unroll
            for (int j = 0; j < 4; j++) {
                float ps = acc[mi][0][j] * asv0 + acc[mi][1][j] * asv1
                         + acc[mi][2][j] * asv2 + acc[mi][3][j] * asv3;
                float pd = acc[mi][0][j] * adv0 + acc[mi][1][j] * adv1
                         + acc[mi][2][j] * adv2 + acc[mi][3][j] * adv3;
#pragma unroll
                for (int off = 1; off <= 8; off <<= 1) {
                    ps += __shfl_xor(ps, off);
                    pd += __shfl_xor(pd, off);
                }
                if (c_l == 0) {
                    int gr = row0 + wr * 64 + mi * 16 + r_h + j;
                    if (gr < M) {
                        atomicAdd(&aSo[gr * HEADS + head], ps);
                        atomicAdd(&aDo[gr * HEADS + head], pd);
                    }
                }
            }
    }
}

// ---- per-dst-node softmax + aggregation (no max shift; deferred normalize),
// 2 edge-parallel groups x 128 channel-threads, 8-row software pipeline.
__global__ __launch_bounds__(256) void agg_kernel(const unsigned short* __restrict__ hb,
                                                  const float* __restrict__ aS,
                                                  const float* __restrict__ aD,
                                                  const int* __restrict__ indptr,
                                                  const int* __restrict__ csr_src,
                                                  const float* __restrict__ bias,
                                                  unsigned short* __restrict__ outb) {
    int i = blockIdx.x;
    int t = threadIdx.x;
    int beg = indptr[i], deg = indptr[i + 1] - beg;
    __shared__ float ssum[HEADS];
    __shared__ float alpha_s[64 * HEADS];
    __shared__ int src_s[64];
    __shared__ float xacc[128 * 8];
    if (t < HEADS) ssum[t] = 0.f;
    float4 adst = *reinterpret_cast<const float4*>(aD + i * HEADS);
    int g = t >> 7, u = t & 127;
    int headu = u >> 5;
    const unsigned short* hp8 = hb + (size_t)u * 8;
    float a0 = 0, a1 = 0, a2 = 0, a3 = 0, a4 = 0, a5 = 0, a6 = 0, a7 = 0;
    __syncthreads();
    for (int c0 = 0; c0 < deg; c0 += 64) {
        int nj = min(64, deg - c0);
        if (t < 64) {
            int s = 0;
            float e0 = 0.f, e1 = 0.f, e2 = 0.f, e3 = 0.f;
            if (t < nj) {
                s = csr_src[beg + c0 + t];
                float4 a = *reinterpret_cast<const float4*>(aS + s * HEADS);
                e0 = __expf(lrelu(a.x + adst.x));
                e1 = __expf(lrelu(a.y + adst.y));
                e2 = __expf(lrelu(a.z + adst.z));
                e3 = __expf(lrelu(a.w + adst.w));
            }
            src_s[t] = s;
            alpha_s[t * 4 + 0] = e0;
            alpha_s[t * 4 + 1] = e1;
            alpha_s[t * 4 + 2] = e2;
            alpha_s[t * 4 + 3] = e3;
            float v0 = e0, v1 = e1, v2 = e2, v3 = e3;
#pragma unroll
            for (int off = 32; off; off >>= 1) {
                v0 += __shfl_xor(v0, off);
                v1 += __shfl_xor(v1, off);
                v2 += __shfl_xor(v2, off);
                v3 += __shfl_xor(v3, off);
            }
            if (t == 0) { ssum[0] += v0; ssum[1] += v1; ssum[2] += v2; ssum[3] += v3; }
        }
        __syncthreads();
        int nG = (nj + 1 - g) >> 1;      // this group's edge count (j = g + 2k)
        int nGr = (nG + 7) & ~7;
#define LDROW(idx) (*reinterpret_cast<const bf16x8*>(hp8 + (size_t)src_s[idx] * D1))
        if (nGr) {
            bf16x8 p0 = LDROW(g);
            bf16x8 p1 = LDROW(g + 2);
            bf16x8 p2 = LDROW(g + 4);
            bf16x8 p3 = LDROW(g + 6);
            bf16x8 p4 = LDROW(g + 8);
            bf16x8 p5 = LDROW(g + 10);
            bf16x8 p6 = LDROW(g + 12);
            bf16x8 p7 = LDROW(g + 14);
            for (int k = 0; k < nGr; k += 8) {
                int j0 = g + 2 * k;
                float w0 = alpha_s[(j0) * 4 + headu];
                float w1 = alpha_s[(j0 + 2) * 4 + headu];
                float w2 = alpha_s[(j0 + 4) * 4 + headu];
                float w3 = alpha_s[(j0 + 6) * 4 + headu];
                float w4 = alpha_s[(j0 + 8) * 4 + headu];
                float w5 = alpha_s[(j0 + 10) * 4 + headu];
                float w6 = alpha_s[(j0 + 12) * 4 + headu];
                float w7 = alpha_s[(j0 + 14) * 4 + headu];
                bf16x8 c0v = p0, c1v = p1, c2v = p2, c3v = p3;
                bf16x8 c4v = p4, c5v = p5, c6v = p6, c7v = p7;
                int jn = j0 + 16;
                p0 = LDROW(min(jn, 63));
                p1 = LDROW(min(jn + 2, 63));
                p2 = LDROW(min(jn + 4, 63));
                p3 = LDROW(min(jn + 6, 63));
                p4 = LDROW(min(jn + 8, 63));
                p5 = LDROW(min(jn + 10, 63));
                p6 = LDROW(min(jn + 12, 63));
                p7 = LDROW(min(jn + 14, 63));
                a0 += w0 * b2f((unsigned short)c0v[0]) + w1 * b2f((unsigned short)c1v[0])
                    + w2 * b2f((unsigned short)c2v[0]) + w3 * b2f((unsigned short)c3v[0])
                    + w4 * b2f((unsigned short)c4v[0]) + w5 * b2f((unsigned short)c5v[0])
                    + w6 * b2f((unsigned short)c6v[0]) + w7 * b2f((unsigned short)c7v[0]);
                a1 += w0 * b2f((unsigned short)c0v[1]) + w1 * b2f((unsigned short)c1v[1])
                    + w2 * b2f((unsigned short)c2v[1]) + w3 * b2f((unsigned short)c3v[1])
                    + w4 * b2f((unsigned short)c4v[1]) + w5 * b2f((unsigned short)c5v[1])
                    + w6 * b2f((unsigned short)c6v[1]) + w7 * b2f((unsigned short)c7v[1]);
                a2 += w0 * b2f((unsigned short)c0v[2]) + w1 * b2f((unsigned short)c1v[2])
                    + w2 * b2f((unsigned short)c2v[2]) + w3 * b2f((unsigned short)c3v[2])
                    + w4 * b2f((unsigned short)c4v[2]) + w5 * b2f((unsigned short)c5v[2])
                    + w6 * b2f((unsigned short)c6v[2]) + w7 * b2f((unsigned short)c7v[2]);
                a3 += w0 * b2f((unsigned short)c0v[3]) + w1 * b2f((unsigned short)c1v[3])
                    + w2 * b2f((unsigned short)c2v[3]) + w3 * b2f((unsigned short)c3v[3])
                    + w4 * b2f((unsigned short)c4v[3]) + w5 * b2f((unsigned short)c5v[3])
                    + w6 * b2f((unsigned short)c6v[3]) + w7 * b2f((unsigned short)c7v[3]);
                a4 += w0 * b2f((unsigned short)c0v[4]) + w1 * b2f((unsigned short)c1v[4])
                    + w2 * b2f((unsigned short)c2v[4]) + w3 * b2f((unsigned short)c3v[4])
                    + w4 * b2f((unsigned short)c4v[4]) + w5 * b2f((unsigned short)c5v[4])
                    + w6 * b2f((unsigned short)c6v[4]) + w7 * b2f((unsigned short)c7v[4]);
                a5 += w0 * b2f((unsigned short)c0v[5]) + w1 * b2f((unsigned short)c1v[5])
                    + w2 * b2f((unsigned short)c2v[5]) + w3 * b2f((unsigned short)c3v[5])
                    + w4 * b2f((unsigned short)c4v[5]) + w5 * b2f((unsigned short)c5v[5])
                    + w6 * b2f((unsigned short)c6v[5]) + w7 * b2f((unsigned short)c7v[5]);
                a6 += w0 * b2f((unsigned short)c0v[6]) + w1 * b2f((unsigned short)c1v[6])
                    + w2 * b2f((unsigned short)c2v[6]) + w3 * b2f((unsigned short)c3v[6])
                    + w4 * b2f((unsigned short)c4v[6]) + w5 * b2f((unsigned short)c5v[6])
                    + w6 * b2f((unsigned short)c6v[6]) + w7 * b2f((unsigned short)c7v[6]);
                a7 += w0 * b2f((unsigned short)c0v[7]) + w1 * b2f((unsigned short)c1v[7])
                    + w2 * b2f((unsigned short)c2v[7]) + w3 * b2f((unsigned short)c3v[7])
                    + w4 * b2f((unsigned short)c4v[7]) + w5 * b2f((unsigned short)c5v[7])
                    + w6 * b2f((unsigned short)c6v[7]) + w7 * b2f((unsigned short)c7v[7]);
            }
        }
#undef LDROW
        __syncthreads();
    }
    if (g == 1) {
        xacc[u * 8 + 0] = a0; xacc[u * 8 + 1] = a1;
        xacc[u * 8 + 2] = a2; xacc[u * 8 + 3] = a3;
        xacc[u * 8 + 4] = a4; xacc[u * 8 + 5] = a5;
        xacc[u * 8 + 6] = a6; xacc[u * 8 + 7] = a7;
    }
    __syncthreads();
    if (g == 0) {
        float inv = 1.f / (ssum[headu] + 1e-16f);
        const float* bp = bias + u * 8;
        bf16x8 ov;
        ov[0] = (short)f2b(fmaxf((a0 + xacc[u * 8 + 0]) * inv + bp[0], 0.f));
        ov[1] = (short)f2b(fmaxf((a1 + xacc[u * 8 + 1]) * inv + bp[1], 0.f));
        ov[2] = (short)f2b(fmaxf((a2 + xacc[u * 8 + 2]) * inv + bp[2], 0.f));
        ov[3] = (short)f2b(fmaxf((a3 + xacc[u * 8 + 3]) * inv + bp[3], 0.f));
        ov[4] = (short)f2b(fmaxf((a4 + xacc[u * 8 + 4]) * inv + bp[4], 0.f));
        ov[5] = (short)f2b(fmaxf((a5 + xacc[u * 8 + 5]) * inv + bp[5], 0.f));
        ov[6] = (short)f2b(fmaxf((a6 + xacc[u * 8 + 6]) * inv + bp[6], 0.f));
        ov[7] = (short)f2b(fmaxf((a7 + xacc[u * 8 + 7]) * inv + bp[7], 0.f));
        *reinterpret_cast<bf16x8*>(outb + (size_t)i * D1 + u * 8) = ov;
    }
}

extern "C" void kernel_launch(void* const* d_in, const int* in_sizes, int n_in,
                              void* d_out, int out_size, void* d_ws, size_t ws_size,
                              hipStream_t stream) {
    const float* x   = (const float*)d_in[0];
    const void*  ei  = d_in[1];
    const float* W1  = (const float*)d_in[2];
    const float* as1 = (const float*)d_in[3];
    const float* ad1 = (const float*)d_in[4];
    const float* b1  = (const float*)d_in[5];
    const float* W2  = (const float*)d_in[6];
    const float* as2 = (const float*)d_in[7];
    const float* ad2 = (const float*)d_in[8];
    const float* b2  = (const float*)d_in[9];
    const float* fcW = (const float*)d_in[10];
    const float* fcb = (const float*)d_in[11];
    float* out = (float*)d_out;

    char* ws = (char*)d_ws;
    size_t o = 0;
    auto carve = [&](size_t bytes) -> char* {
        char* p = ws + o;
        o = (o + bytes + 255) & ~(size_t)255;
        return p;
    };
    unsigned short* xb   = (unsigned short*)carve((size_t)NN * IN_DIM * 2);
    unsigned short* hb   = (unsigned short*)carve((size_t)NN * D1 * 2);
    unsigned short* x2b  = (unsigned short*)carve((size_t)NN * D1 * 2);
    unsigned short* W1t  = (unsigned short*)carve((size_t)D1 * IN_DIM * 2);
    unsigned short* W2t  = (unsigned short*)carve((size_t)D1 * D1 * 2);
    unsigned short* fcWt = (unsigned short*)carve((size_t)OUT_DIM * D1 * 2);
    float* aS   = (float*)carve((size_t)NN * HEADS * 4);
    float* aD   = (float*)carve((size_t)NN * HEADS * 4);
    int* counts = (int*)carve((size_t)NN * 4);
    int* cursor = (int*)carve((size_t)NN * 4);
    int* indptr = (int*)carve((size_t)(NN + 1) * 4);
    int* csr_src= (int*)carve((size_t)NET * 4);
    int* flag   = (int*)carve(4);
    (void)ws_size; (void)in_sizes; (void)n_in; (void)out_size;

    // CSR build (dtype-agnostic edge loads) + zero att accumulators
    init_kernel<<<(NN + 255) / 256, 256, 0, stream>>>((const int*)ei, flag, counts, cursor, aS, aD);
    count_kernel<<<(NET + 255) / 256, 256, 0, stream>>>(ei, flag, counts);
    scan_kernel<<<1, 256, 0, stream>>>(counts, indptr);
    fill_kernel<<<(NET + 255) / 256, 256, 0, stream>>>(ei, flag, indptr, cursor, csr_src);

    // fused conversions (cvt + 3 transposes)
    prep_kernel<<<CVT_NB + TP1_NB + TP2_NB + TP3_NB, 256, 0, stream>>>(
        x, xb, W1, W1t, W2, W2t, fcW, fcWt);

    const int MB = (NN + BM - 1) / BM;  // 79
    // layer 1 (gemm computes h and fused att dots)
    gemm128<<<dim3(MB, D1 / BN), 256, 0, stream>>>(xb, W1t, nullptr, nullptr, hb,
                                                   as1, ad1, aS, aD, NN, D1, IN_DIM);
    agg_kernel<<<NN, 256, 0, stream>>>(hb, aS, aD, indptr, csr_src, b1, x2b);
    zatt_kernel<<<(NN * HEADS + 255) / 256, 256, 0, stream>>>(aS, aD);
    // layer 2
    gemm128<<<dim3(MB, D1 / BN), 256, 0, stream>>>(x2b, W2t, nullptr, nullptr, hb,
                                                   as2, ad2, aS, aD, NN, D1, D1);
    agg_kernel<<<NN, 256, 0, stream>>>(hb, aS, aD, indptr, csr_src, b2, x2b);
    // final fc (bias, f32 out, no att)
    gemm128<<<dim3(MB, OUT_DIM / BN), 256, 0, stream>>>(x2b, fcWt, fcb, out, nullptr,
                                                        nullptr, nullptr, nullptr, nullptr,
                                                        NN, OUT_DIM, D1);
}

// Round 5
// 275.457 us; speedup vs baseline: 1.0544x; 1.0544x over previous
//
#include <hip/hip_runtime.h>
#include <hip/hip_bf16.h>

#define NN 10000
#define NE 160000
#define NET 170000   // edges + self loops
#define IN_DIM 512
#define D1 1024      // HEADS*HID
#define HEADS 4
#define HID 256
#define OUT_DIM 512
#define NEG_SLOPE 0.2f

typedef __attribute__((ext_vector_type(8))) short bf16x8;
typedef __attribute__((ext_vector_type(4))) float f32x4;

__device__ inline float b2f(unsigned short b) {
    union { unsigned u; float f; } x; x.u = ((unsigned)b) << 16; return x.f;
}
__device__ inline unsigned short f2b(float f) {
    union { float f; unsigned u; } x; x.f = f;
    unsigned u = x.u;
    unsigned r = u + 0x7FFFu + ((u >> 16) & 1u);
    return (unsigned short)(r >> 16);
}
__device__ inline float lrelu(float v) { return v > 0.f ? v : NEG_SLOPE * v; }

// ---- init: zero counts/cursor; block 0 detects edge_index dtype
// (int64 -> high words of first 500 values are all 0)
__global__ void init_kernel(const int* ei32, int* flag, int* counts, int* cursor) {
    int i = blockIdx.x * blockDim.x + threadIdx.x;
    if (i < NN) { counts[i] = 0; cursor[i] = 0; }
    if (blockIdx.x == 0) {
        __shared__ int nz;
        if (threadIdx.x == 0) nz = 0;
        __syncthreads();
        int acc = 0;
        for (int k = threadIdx.x; k < 500; k += 256) acc |= ei32[2 * k + 1];
        if (acc) atomicOr(&nz, 1);
        __syncthreads();
        if (threadIdx.x == 0) flag[0] = (nz == 0) ? 1 : 0;
    }
}

__device__ inline void load_edge(const void* ei, int f64, int e, int& s, int& d) {
    if (f64) {
        const long long* p = (const long long*)ei;
        s = (int)p[e]; d = (int)p[NE + e];
    } else {
        const int* p = (const int*)ei;
        s = p[e]; d = p[NE + e];
    }
}

__global__ void count_kernel(const void* ei, const int* flag, int* counts) {
    int e = blockIdx.x * blockDim.x + threadIdx.x;
    if (e >= NET) return;
    int s, d;
    if (e < NE) load_edge(ei, *flag, e, s, d);
    else d = e - NE;
    atomicAdd(&counts[d], 1);
}

__global__ __launch_bounds__(256) void scan_kernel(const int* counts, int* indptr) {
    __shared__ int part[256];
    int t = threadIdx.x;
    int base = t * 40;
    int local[40];
    int sum = 0;
#pragma unroll
    for (int k = 0; k < 40; k++) {
        int i = base + k;
        int c = (i < NN) ? counts[i] : 0;
        local[k] = sum;
        sum += c;
    }
    part[t] = sum;
    __syncthreads();
    for (int off = 1; off < 256; off <<= 1) {
        int v = (t >= off) ? part[t - off] : 0;
        __syncthreads();
        part[t] += v;
        __syncthreads();
    }
    int excl = part[t] - sum;
#pragma unroll
    for (int k = 0; k < 40; k++) {
        int i = base + k;
        if (i < NN) indptr[i] = excl + local[k];
    }
    if (t == 255) indptr[NN] = part[255];
}

__global__ void fill_kernel(const void* ei, const int* flag, const int* indptr,
                            int* cursor, int* csr_src) {
    int e = blockIdx.x * blockDim.x + threadIdx.x;
    if (e >= NET) return;
    int s, d;
    if (e < NE) load_edge(ei, *flag, e, s, d);
    else { s = e - NE; d = s; }
    int pos = indptr[d] + atomicAdd(&cursor[d], 1);
    csr_src[pos] = s;
}

// ---- prep: fused x->bf16 convert + 3 weight transposes (sectioned 1D grid)
__device__ void tpose_tile(const float* __restrict__ in, unsigned short* __restrict__ out,
                           int R, int C, int bx, int by) {
    __shared__ float tile[32][33];
    int tx = threadIdx.x & 31, ty = threadIdx.x >> 5;
    int c = bx * 32 + tx;
#pragma unroll
    for (int r0 = 0; r0 < 32; r0 += 8) {
        int r = by * 32 + ty + r0;
        tile[ty + r0][tx] = in[(size_t)r * C + c];
    }
    __syncthreads();
    int oc = by * 32 + tx;
#pragma unroll
    for (int r0 = 0; r0 < 32; r0 += 8) {
        int orow = bx * 32 + ty + r0;
        out[(size_t)orow * R + oc] = f2b(tile[tx][ty + r0]);
    }
}

#define CVT_NB 5000   // NN*IN_DIM/4/256
#define TP1_NB 512    // (D1/32)*(IN_DIM/32)
#define TP2_NB 1024   // (D1/32)*(D1/32)
#define TP3_NB 512    // (OUT_DIM/32)*(D1/32)
__global__ __launch_bounds__(256) void prep_kernel(
    const float* __restrict__ x, unsigned short* __restrict__ xb,
    const float* __restrict__ W1, unsigned short* __restrict__ W1t,
    const float* __restrict__ W2, unsigned short* __restrict__ W2t,
    const float* __restrict__ fcW, unsigned short* __restrict__ fcWt) {
    int b = blockIdx.x;
    if (b < CVT_NB) {
        int i = b * 256 + threadIdx.x;
        float4 v = reinterpret_cast<const float4*>(x)[i];
        ushort4 o;
        o.x = f2b(v.x); o.y = f2b(v.y); o.z = f2b(v.z); o.w = f2b(v.w);
        reinterpret_cast<ushort4*>(xb)[i] = o;
        return;
    }
    b -= CVT_NB;
    if (b < TP1_NB) { tpose_tile(W1, W1t, IN_DIM, D1, b & 31, b >> 5); return; }
    b -= TP1_NB;
    if (b < TP2_NB) { tpose_tile(W2, W2t, D1, D1, b & 31, b >> 5); return; }
    b -= TP2_NB;
    tpose_tile(fcW, fcWt, D1, OUT_DIM, b & 15, b >> 4);
}

// ---- C[M][N] = A[M][K](bf16) @ B[N][K](bf16)^T
// 128x128 tile, BK=64, 4 waves (2x2 of 64x64), global_load_lds width 16,
// XOR-swizzled LDS (pre-swizzled global source cols, swizzled ds_read),
// bijective XCD-aware block swizzle.
#define BM 128
#define BN 128
#define BK 64
__global__ __launch_bounds__(256) void gemm128(
    const unsigned short* __restrict__ A, const unsigned short* __restrict__ B,
    const float* __restrict__ bias, float* __restrict__ Cf, unsigned short* __restrict__ Cb,
    int M, int N, int K, int NB) {
    __shared__ __align__(16) unsigned short As[BM * BK];  // 16 KB
    __shared__ __align__(16) unsigned short Bs[BN * BK];  // 16 KB
    int t = threadIdx.x;
    // bijective XCD swizzle (m204): chunk the grid so each XCD gets
    // ~nwg/8 consecutive tiles; decode nx=wg/NB, ny=wg%NB so a chunk
    // covers all col-blocks of ~10 contiguous row-panels.
    int nwg = gridDim.x;
    int q = nwg >> 3, r = nwg & 7;
    int xcd = blockIdx.x & 7, jj = blockIdx.x >> 3;
    int wg = (xcd < r ? xcd * (q + 1) : r * (q + 1) + (xcd - r) * q) + jj;
    int row0 = (wg / NB) * BM, col0 = (wg % NB) * BN;

    int w = t >> 6, l = t & 63;
    int wr = w >> 1, wc = w & 1;
    f32x4 acc[4][4] = {};

    // staging: per issue i (0..3), thread covers 16B; source column is
    // inverse-swizzled so the LINEAR gload_lds write produces the swizzled
    // layout: LDS[row*128B + (col2 ^ ((row&7)<<4))] = A[row][col]
    int srow = w * 8 + (l >> 3);                 // row within 32-row issue chunk
    int scs = (((l & 7) ^ (l >> 3)) * 8);        // source col in shorts
    const unsigned short* ap0 = A + (size_t)min(row0 +  0 + srow, M - 1) * K + scs;
    const unsigned short* ap1 = A + (size_t)min(row0 + 32 + srow, M - 1) * K + scs;
    const unsigned short* ap2 = A + (size_t)min(row0 + 64 + srow, M - 1) * K + scs;
    const unsigned short* ap3 = A + (size_t)min(row0 + 96 + srow, M - 1) * K + scs;
    const unsigned short* bp0 = B + (size_t)(col0 +  0 + srow) * K + scs;
    const unsigned short* bp1 = B + (size_t)(col0 + 32 + srow) * K + scs;
    const unsigned short* bp2 = B + (size_t)(col0 + 64 + srow) * K + scs;
    const unsigned short* bp3 = B + (size_t)(col0 + 96 + srow) * K + scs;
    unsigned short* asd0 = As + 0 * 2048 + w * 512;   // wave-uniform LDS dests
    unsigned short* asd1 = As + 1 * 2048 + w * 512;
    unsigned short* asd2 = As + 2 * 2048 + w * 512;
    unsigned short* asd3 = As + 3 * 2048 + w * 512;
    unsigned short* bsd0 = Bs + 0 * 2048 + w * 512;
    unsigned short* bsd1 = Bs + 1 * 2048 + w * 512;
    unsigned short* bsd2 = Bs + 2 * 2048 + w * 512;
    unsigned short* bsd3 = Bs + 3 * 2048 + w * 512;

    int rr = l & 15;
    int rb = (rr & 7) << 4;          // per-row byte XOR for ds_read
    int kb0 = (l >> 4) << 4;         // 0,16,32,48 byte within K-slice
    const char* Ab = (const char*)As;
    const char* Bb = (const char*)Bs;

#define GLD(src, dst) __builtin_amdgcn_global_load_lds( \
        (const __attribute__((address_space(1))) void*)(src), \
        (__attribute__((address_space(3))) void*)(dst), 16, 0, 0)

    for (int k0 = 0; k0 < K; k0 += BK) {
        GLD(ap0, asd0); GLD(ap1, asd1); GLD(ap2, asd2); GLD(ap3, asd3);
        GLD(bp0, bsd0); GLD(bp1, bsd1); GLD(bp2, bsd2); GLD(bp3, bsd3);
        ap0 += BK; ap1 += BK; ap2 += BK; ap3 += BK;
        bp0 += BK; bp1 += BK; bp2 += BK; bp3 += BK;
        __syncthreads();

#pragma unroll
        for (int ks = 0; ks < 2; ks++) {
            int kb = ((ks << 6) | kb0) ^ rb;
            bf16x8 af[4], bfv[4];
#pragma unroll
            for (int mi = 0; mi < 4; mi++)
                af[mi] = *reinterpret_cast<const bf16x8*>(
                    Ab + (wr * 64 + mi * 16 + rr) * 128 + kb);
#pragma unroll
            for (int ni = 0; ni < 4; ni++)
                bfv[ni] = *reinterpret_cast<const bf16x8*>(
                    Bb + (wc * 64 + ni * 16 + rr) * 128 + kb);
#pragma unroll
            for (int mi = 0; mi < 4; mi++)
#pragma unroll
                for (int ni = 0; ni < 4; ni++)
                    acc[mi][ni] = __builtin_amdgcn_mfma_f32_16x16x32_bf16(
                        af[mi], bfv[ni], acc[mi][ni], 0, 0, 0);
        }
        __syncthreads();
    }
#undef GLD

    // C/D: col = lane&15, row = (lane>>4)*4 + j
    int c_l = l & 15, r_h = (l >> 4) * 4;
#pragma unroll
    for (int mi = 0; mi < 4; mi++)
#pragma unroll
        for (int ni = 0; ni < 4; ni++) {
            int gc = col0 + wc * 64 + ni * 16 + c_l;
#pragma unroll
            for (int j = 0; j < 4; j++) {
                int gr = row0 + wr * 64 + mi * 16 + r_h + j;
                if (gr < M) {
                    float v = acc[mi][ni][j];
                    if (bias) v += bias[gc];
                    if (Cf) Cf[(size_t)gr * N + gc] = v;
                    if (Cb) Cb[(size_t)gr * N + gc] = f2b(v);
                }
            }
        }
}

// ---- a_src/a_dst: per node, per head dot(h[n,h,:], att[h,:]); wave == head
__global__ __launch_bounds__(256) void att_kernel(const unsigned short* __restrict__ hb,
                                                  const float* __restrict__ att_s,
                                                  const float* __restrict__ att_d,
                                                  float* __restrict__ aS, float* __restrict__ aD) {
    int n = blockIdx.x;
    int t = threadIdx.x;
    int head = t >> 6, lane = t & 63;
    const unsigned short* hrow = hb + (size_t)n * D1 + head * HID + lane * 4;
    ushort4 hv = *reinterpret_cast<const ushort4*>(hrow);
    float4 as = *reinterpret_cast<const float4*>(att_s + head * HID + lane * 4);
    float4 ad = *reinterpret_cast<const float4*>(att_d + head * HID + lane * 4);
    float h0 = b2f(hv.x), h1 = b2f(hv.y), h2 = b2f(hv.z), h3 = b2f(hv.w);
    float ps = h0 * as.x + h1 * as.y + h2 * as.z + h3 * as.w;
    float pd = h0 * ad.x + h1 * ad.y + h2 * ad.z + h3 * ad.w;
#pragma unroll
    for (int off = 32; off; off >>= 1) {
        ps += __shfl_xor(ps, off);
        pd += __shfl_xor(pd, off);
    }
    if (lane == 0) {
        aS[n * HEADS + head] = ps;
        aD[n * HEADS + head] = pd;
    }
}

// ---- per-dst-node softmax + aggregation (no max shift; deferred normalize),
// 2 edge-parallel groups x 128 channel-threads, 8-row software pipeline.
__global__ __launch_bounds__(256) void agg_kernel(const unsigned short* __restrict__ hb,
                                                  const float* __restrict__ aS,
                                                  const float* __restrict__ aD,
                                                  const int* __restrict__ indptr,
                                                  const int* __restrict__ csr_src,
                                                  const float* __restrict__ bias,
                                                  unsigned short* __restrict__ outb) {
    int i = blockIdx.x;
    int t = threadIdx.x;
    int beg = indptr[i], deg = indptr[i + 1] - beg;
    __shared__ float ssum[HEADS];
    __shared__ float alpha_s[64 * HEADS];
    __shared__ int src_s[64];
    __shared__ float xacc[128 * 8];
    if (t < HEADS) ssum[t] = 0.f;
    float4 adst = *reinterpret_cast<const float4*>(aD + i * HEADS);
    int g = t >> 7, u = t & 127;
    int headu = u >> 5;
    const unsigned short* hp8 = hb + (size_t)u * 8;
    float a0 = 0, a1 = 0, a2 = 0, a3 = 0, a4 = 0, a5 = 0, a6 = 0, a7 = 0;
    __syncthreads();
    for (int c0 = 0; c0 < deg; c0 += 64) {
        int nj = min(64, deg - c0);
        if (t < 64) {
            int s = 0;
            float e0 = 0.f, e1 = 0.f, e2 = 0.f, e3 = 0.f;
            if (t < nj) {
                s = csr_src[beg + c0 + t];
                float4 a = *reinterpret_cast<const float4*>(aS + s * HEADS);
                e0 = __expf(lrelu(a.x + adst.x));
                e1 = __expf(lrelu(a.y + adst.y));
                e2 = __expf(lrelu(a.z + adst.z));
                e3 = __expf(lrelu(a.w + adst.w));
            }
            src_s[t] = s;
            alpha_s[t * 4 + 0] = e0;
            alpha_s[t * 4 + 1] = e1;
            alpha_s[t * 4 + 2] = e2;
            alpha_s[t * 4 + 3] = e3;
            float v0 = e0, v1 = e1, v2 = e2, v3 = e3;
#pragma unroll
            for (int off = 32; off; off >>= 1) {
                v0 += __shfl_xor(v0, off);
                v1 += __shfl_xor(v1, off);
                v2 += __shfl_xor(v2, off);
                v3 += __shfl_xor(v3, off);
            }
            if (t == 0) { ssum[0] += v0; ssum[1] += v1; ssum[2] += v2; ssum[3] += v3; }
        }
        __syncthreads();
        int nG = (nj + 1 - g) >> 1;      // this group's edge count (j = g + 2k)
        int nGr = (nG + 7) & ~7;
#define LDROW(idx) (*reinterpret_cast<const bf16x8*>(hp8 + (size_t)src_s[idx] * D1))
        if (nGr) {
            bf16x8 p0 = LDROW(g);
            bf16x8 p1 = LDROW(g + 2);
            bf16x8 p2 = LDROW(g + 4);
            bf16x8 p3 = LDROW(g + 6);
            bf16x8 p4 = LDROW(g + 8);
            bf16x8 p5 = LDROW(g + 10);
            bf16x8 p6 = LDROW(g + 12);
            bf16x8 p7 = LDROW(g + 14);
            for (int k = 0; k < nGr; k += 8) {
                int j0 = g + 2 * k;
                float w0 = alpha_s[(j0) * 4 + headu];
                float w1 = alpha_s[(j0 + 2) * 4 + headu];
                float w2 = alpha_s[(j0 + 4) * 4 + headu];
                float w3 = alpha_s[(j0 + 6) * 4 + headu];
                float w4 = alpha_s[(j0 + 8) * 4 + headu];
                float w5 = alpha_s[(j0 + 10) * 4 + headu];
                float w6 = alpha_s[(j0 + 12) * 4 + headu];
                float w7 = alpha_s[(j0 + 14) * 4 + headu];
                bf16x8 c0v = p0, c1v = p1, c2v = p2, c3v = p3;
                bf16x8 c4v = p4, c5v = p5, c6v = p6, c7v = p7;
                int jn = j0 + 16;
                p0 = LDROW(min(jn, 63));
                p1 = LDROW(min(jn + 2, 63));
                p2 = LDROW(min(jn + 4, 63));
                p3 = LDROW(min(jn + 6, 63));
                p4 = LDROW(min(jn + 8, 63));
                p5 = LDROW(min(jn + 10, 63));
                p6 = LDROW(min(jn + 12, 63));
                p7 = LDROW(min(jn + 14, 63));
                a0 += w0 * b2f((unsigned short)c0v[0]) + w1 * b2f((unsigned short)c1v[0])
                    + w2 * b2f((unsigned short)c2v[0]) + w3 * b2f((unsigned short)c3v[0])
                    + w4 * b2f((unsigned short)c4v[0]) + w5 * b2f((unsigned short)c5v[0])
                    + w6 * b2f((unsigned short)c6v[0]) + w7 * b2f((unsigned short)c7v[0]);
                a1 += w0 * b2f((unsigned short)c0v[1]) + w1 * b2f((unsigned short)c1v[1])
                    + w2 * b2f((unsigned short)c2v[1]) + w3 * b2f((unsigned short)c3v[1])
                    + w4 * b2f((unsigned short)c4v[1]) + w5 * b2f((unsigned short)c5v[1])
                    + w6 * b2f((unsigned short)c6v[1]) + w7 * b2f((unsigned short)c7v[1]);
                a2 += w0 * b2f((unsigned short)c0v[2]) + w1 * b2f((unsigned short)c1v[2])
                    + w2 * b2f((unsigned short)c2v[2]) + w3 * b2f((unsigned short)c3v[2])
                    + w4 * b2f((unsigned short)c4v[2]) + w5 * b2f((unsigned short)c5v[2])
                    + w6 * b2f((unsigned short)c6v[2]) + w7 * b2f((unsigned short)c7v[2]);
                a3 += w0 * b2f((unsigned short)c0v[3]) + w1 * b2f((unsigned short)c1v[3])
                    + w2 * b2f((unsigned short)c2v[3]) + w3 * b2f((unsigned short)c3v[3])
                    + w4 * b2f((unsigned short)c4v[3]) + w5 * b2f((unsigned short)c5v[3])
                    + w6 * b2f((unsigned short)c6v[3]) + w7 * b2f((unsigned short)c7v[3]);
                a4 += w0 * b2f((unsigned short)c0v[4]) + w1 * b2f((unsigned short)c1v[4])
                    + w2 * b2f((unsigned short)c2v[4]) + w3 * b2f((unsigned short)c3v[4])
                    + w4 * b2f((unsigned short)c4v[4]) + w5 * b2f((unsigned short)c5v[4])
                    + w6 * b2f((unsigned short)c6v[4]) + w7 * b2f((unsigned short)c7v[4]);
                a5 += w0 * b2f((unsigned short)c0v[5]) + w1 * b2f((unsigned short)c1v[5])
                    + w2 * b2f((unsigned short)c2v[5]) + w3 * b2f((unsigned short)c3v[5])
                    + w4 * b2f((unsigned short)c4v[5]) + w5 * b2f((unsigned short)c5v[5])
                    + w6 * b2f((unsigned short)c6v[5]) + w7 * b2f((unsigned short)c7v[5]);
                a6 += w0 * b2f((unsigned short)c0v[6]) + w1 * b2f((unsigned short)c1v[6])
                    + w2 * b2f((unsigned short)c2v[6]) + w3 * b2f((unsigned short)c3v[6])
                    + w4 * b2f((unsigned short)c4v[6]) + w5 * b2f((unsigned short)c5v[6])
                    + w6 * b2f((unsigned short)c6v[6]) + w7 * b2f((unsigned short)c7v[6]);
                a7 += w0 * b2f((unsigned short)c0v[7]) + w1 * b2f((unsigned short)c1v[7])
                    + w2 * b2f((unsigned short)c2v[7]) + w3 * b2f((unsigned short)c3v[7])
                    + w4 * b2f((unsigned short)c4v[7]) + w5 * b2f((unsigned short)c5v[7])
                    + w6 * b2f((unsigned short)c6v[7]) + w7 * b2f((unsigned short)c7v[7]);
            }
        }
#undef LDROW
        __syncthreads();
    }
    if (g == 1) {
        xacc[u * 8 + 0] = a0; xacc[u * 8 + 1] = a1;
        xacc[u * 8 + 2] = a2; xacc[u * 8 + 3] = a3;
        xacc[u * 8 + 4] = a4; xacc[u * 8 + 5] = a5;
        xacc[u * 8 + 6] = a6; xacc[u * 8 + 7] = a7;
    }
    __syncthreads();
    if (g == 0) {
        float inv = 1.f / (ssum[headu] + 1e-16f);
        const float* bp = bias + u * 8;
        bf16x8 ov;
        ov[0] = (short)f2b(fmaxf((a0 + xacc[u * 8 + 0]) * inv + bp[0], 0.f));
        ov[1] = (short)f2b(fmaxf((a1 + xacc[u * 8 + 1]) * inv + bp[1], 0.f));
        ov[2] = (short)f2b(fmaxf((a2 + xacc[u * 8 + 2]) * inv + bp[2], 0.f));
        ov[3] = (short)f2b(fmaxf((a3 + xacc[u * 8 + 3]) * inv + bp[3], 0.f));
        ov[4] = (short)f2b(fmaxf((a4 + xacc[u * 8 + 4]) * inv + bp[4], 0.f));
        ov[5] = (short)f2b(fmaxf((a5 + xacc[u * 8 + 5]) * inv + bp[5], 0.f));
        ov[6] = (short)f2b(fmaxf((a6 + xacc[u * 8 + 6]) * inv + bp[6], 0.f));
        ov[7] = (short)f2b(fmaxf((a7 + xacc[u * 8 + 7]) * inv + bp[7], 0.f));
        *reinterpret_cast<bf16x8*>(outb + (size_t)i * D1 + u * 8) = ov;
    }
}

extern "C" void kernel_launch(void* const* d_in, const int* in_sizes, int n_in,
                              void* d_out, int out_size, void* d_ws, size_t ws_size,
                              hipStream_t stream) {
    const float* x   = (const float*)d_in[0];
    const void*  ei  = d_in[1];
    const float* W1  = (const float*)d_in[2];
    const float* as1 = (const float*)d_in[3];
    const float* ad1 = (const float*)d_in[4];
    const float* b1  = (const float*)d_in[5];
    const float* W2  = (const float*)d_in[6];
    const float* as2 = (const float*)d_in[7];
    const float* ad2 = (const float*)d_in[8];
    const float* b2  = (const float*)d_in[9];
    const float* fcW = (const float*)d_in[10];
    const float* fcb = (const float*)d_in[11];
    float* out = (float*)d_out;

    char* ws = (char*)d_ws;
    size_t o = 0;
    auto carve = [&](size_t bytes) -> char* {
        char* p = ws + o;
        o = (o + bytes + 255) & ~(size_t)255;
        return p;
    };
    unsigned short* xb   = (unsigned short*)carve((size_t)NN * IN_DIM * 2);
    unsigned short* hb   = (unsigned short*)carve((size_t)NN * D1 * 2);
    unsigned short* x2b  = (unsigned short*)carve((size_t)NN * D1 * 2);
    unsigned short* W1t  = (unsigned short*)carve((size_t)D1 * IN_DIM * 2);
    unsigned short* W2t  = (unsigned short*)carve((size_t)D1 * D1 * 2);
    unsigned short* fcWt = (unsigned short*)carve((size_t)OUT_DIM * D1 * 2);
    float* aS   = (float*)carve((size_t)NN * HEADS * 4);
    float* aD   = (float*)carve((size_t)NN * HEADS * 4);
    int* counts = (int*)carve((size_t)NN * 4);
    int* cursor = (int*)carve((size_t)NN * 4);
    int* indptr = (int*)carve((size_t)(NN + 1) * 4);
    int* csr_src= (int*)carve((size_t)NET * 4);
    int* flag   = (int*)carve(4);
    (void)ws_size; (void)in_sizes; (void)n_in; (void)out_size;

    // CSR build (dtype-agnostic edge loads)
    init_kernel<<<(NN + 255) / 256, 256, 0, stream>>>((const int*)ei, flag, counts, cursor);
    count_kernel<<<(NET + 255) / 256, 256, 0, stream>>>(ei, flag, counts);
    scan_kernel<<<1, 256, 0, stream>>>(counts, indptr);
    fill_kernel<<<(NET + 255) / 256, 256, 0, stream>>>(ei, flag, indptr, cursor, csr_src);

    // fused conversions (cvt + 3 transposes)
    prep_kernel<<<CVT_NB + TP1_NB + TP2_NB + TP3_NB, 256, 0, stream>>>(
        x, xb, W1, W1t, W2, W2t, fcW, fcWt);

    const int MB = (NN + BM - 1) / BM;  // 79
    // layer 1
    gemm128<<<MB * (D1 / BN), 256, 0, stream>>>(xb, W1t, nullptr, nullptr, hb,
                                                NN, D1, IN_DIM, D1 / BN);
    att_kernel<<<NN, 256, 0, stream>>>(hb, as1, ad1, aS, aD);
    agg_kernel<<<NN, 256, 0, stream>>>(hb, aS, aD, indptr, csr_src, b1, x2b);
    // layer 2
    gemm128<<<MB * (D1 / BN), 256, 0, stream>>>(x2b, W2t, nullptr, nullptr, hb,
                                                NN, D1, D1, D1 / BN);
    att_kernel<<<NN, 256, 0, stream>>>(hb, as2, ad2, aS, aD);
    agg_kernel<<<NN, 256, 0, stream>>>(hb, aS, aD, indptr, csr_src, b2, x2b);
    // final fc (bias, f32 out)
    gemm128<<<MB * (OUT_DIM / BN), 256, 0, stream>>>(x2b, fcWt, fcb, out, nullptr,
                                                     NN, OUT_DIM, D1, OUT_DIM / BN);
}

// Round 6
// 269.206 us; speedup vs baseline: 1.0789x; 1.0232x over previous
//
#include <hip/hip_runtime.h>
#include <hip/hip_bf16.h>

#define NN 10000
#define NE 160000
#define NET 170000   // edges + self loops
#define IN_DIM 512
#define D1 1024      // HEADS*HID
#define HEADS 4
#define HID 256
#define OUT_DIM 512
#define NEG_SLOPE 0.2f

typedef __attribute__((ext_vector_type(8))) short bf16x8;
typedef __attribute__((ext_vector_type(4))) float f32x4;

__device__ inline float b2f(unsigned short b) {
    union { unsigned u; float f; } x; x.u = ((unsigned)b) << 16; return x.f;
}
__device__ inline unsigned short f2b(float f) {
    union { float f; unsigned u; } x; x.f = f;
    unsigned u = x.u;
    unsigned r = u + 0x7FFFu + ((u >> 16) & 1u);
    return (unsigned short)(r >> 16);
}
__device__ inline float lrelu(float v) { return v > 0.f ? v : NEG_SLOPE * v; }

// ---- init: zero counts/cursor; block 0 detects edge_index dtype
// (int64 -> high words of first 500 values are all 0)
__global__ void init_kernel(const int* ei32, int* flag, int* counts, int* cursor) {
    int i = blockIdx.x * blockDim.x + threadIdx.x;
    if (i < NN) { counts[i] = 0; cursor[i] = 0; }
    if (blockIdx.x == 0) {
        __shared__ int nz;
        if (threadIdx.x == 0) nz = 0;
        __syncthreads();
        int acc = 0;
        for (int k = threadIdx.x; k < 500; k += 256) acc |= ei32[2 * k + 1];
        if (acc) atomicOr(&nz, 1);
        __syncthreads();
        if (threadIdx.x == 0) flag[0] = (nz == 0) ? 1 : 0;
    }
}

__device__ inline void load_edge(const void* ei, int f64, int e, int& s, int& d) {
    if (f64) {
        const long long* p = (const long long*)ei;
        s = (int)p[e]; d = (int)p[NE + e];
    } else {
        const int* p = (const int*)ei;
        s = p[e]; d = p[NE + e];
    }
}

__global__ void count_kernel(const void* ei, const int* flag, int* counts) {
    int e = blockIdx.x * blockDim.x + threadIdx.x;
    if (e >= NET) return;
    int s, d;
    if (e < NE) load_edge(ei, *flag, e, s, d);
    else d = e - NE;
    atomicAdd(&counts[d], 1);
}

__global__ __launch_bounds__(256) void scan_kernel(const int* counts, int* indptr) {
    __shared__ int part[256];
    int t = threadIdx.x;
    int base = t * 40;
    int local[40];
    int sum = 0;
#pragma unroll
    for (int k = 0; k < 40; k++) {
        int i = base + k;
        int c = (i < NN) ? counts[i] : 0;
        local[k] = sum;
        sum += c;
    }
    part[t] = sum;
    __syncthreads();
    for (int off = 1; off < 256; off <<= 1) {
        int v = (t >= off) ? part[t - off] : 0;
        __syncthreads();
        part[t] += v;
        __syncthreads();
    }
    int excl = part[t] - sum;
#pragma unroll
    for (int k = 0; k < 40; k++) {
        int i = base + k;
        if (i < NN) indptr[i] = excl + local[k];
    }
    if (t == 255) indptr[NN] = part[255];
}

__global__ void fill_kernel(const void* ei, const int* flag, const int* indptr,
                            int* cursor, int* csr_src) {
    int e = blockIdx.x * blockDim.x + threadIdx.x;
    if (e >= NET) return;
    int s, d;
    if (e < NE) load_edge(ei, *flag, e, s, d);
    else { s = e - NE; d = s; }
    int pos = indptr[d] + atomicAdd(&cursor[d], 1);
    csr_src[pos] = s;
}

// ---- prep: fused x->bf16 convert + 3 weight transposes (sectioned 1D grid)
__device__ void tpose_tile(const float* __restrict__ in, unsigned short* __restrict__ out,
                           int R, int C, int bx, int by) {
    __shared__ float tile[32][33];
    int tx = threadIdx.x & 31, ty = threadIdx.x >> 5;
    int c = bx * 32 + tx;
#pragma unroll
    for (int r0 = 0; r0 < 32; r0 += 8) {
        int r = by * 32 + ty + r0;
        tile[ty + r0][tx] = in[(size_t)r * C + c];
    }
    __syncthreads();
    int oc = by * 32 + tx;
#pragma unroll
    for (int r0 = 0; r0 < 32; r0 += 8) {
        int orow = bx * 32 + ty + r0;
        out[(size_t)orow * R + oc] = f2b(tile[tx][ty + r0]);
    }
}

#define CVT_NB 5000   // NN*IN_DIM/4/256
#define TP1_NB 512    // (D1/32)*(IN_DIM/32)
#define TP2_NB 1024   // (D1/32)*(D1/32)
#define TP3_NB 512    // (OUT_DIM/32)*(D1/32)
__global__ __launch_bounds__(256) void prep_kernel(
    const float* __restrict__ x, unsigned short* __restrict__ xb,
    const float* __restrict__ W1, unsigned short* __restrict__ W1t,
    const float* __restrict__ W2, unsigned short* __restrict__ W2t,
    const float* __restrict__ fcW, unsigned short* __restrict__ fcWt) {
    int b = blockIdx.x;
    if (b < CVT_NB) {
        int i = b * 256 + threadIdx.x;
        float4 v = reinterpret_cast<const float4*>(x)[i];
        ushort4 o;
        o.x = f2b(v.x); o.y = f2b(v.y); o.z = f2b(v.z); o.w = f2b(v.w);
        reinterpret_cast<ushort4*>(xb)[i] = o;
        return;
    }
    b -= CVT_NB;
    if (b < TP1_NB) { tpose_tile(W1, W1t, IN_DIM, D1, b & 31, b >> 5); return; }
    b -= TP1_NB;
    if (b < TP2_NB) { tpose_tile(W2, W2t, D1, D1, b & 31, b >> 5); return; }
    b -= TP2_NB;
    tpose_tile(fcW, fcWt, D1, OUT_DIM, b & 15, b >> 4);
}

// ---- C[M][N] = A[M][K](bf16) @ B[N][K](bf16)^T
// 128x128 tile, BK=64, 4 waves (2x2 of 64x64), global_load_lds width 16,
// XOR-swizzled LDS (pre-swizzled global source cols, swizzled ds_read),
// bijective XCD-aware block swizzle.
#define BM 128
#define BN 128
#define BK 64
__global__ __launch_bounds__(256) void gemm128(
    const unsigned short* __restrict__ A, const unsigned short* __restrict__ B,
    const float* __restrict__ bias, float* __restrict__ Cf, unsigned short* __restrict__ Cb,
    int M, int N, int K, int NB) {
    __shared__ __align__(16) unsigned short As[BM * BK];  // 16 KB
    __shared__ __align__(16) unsigned short Bs[BN * BK];  // 16 KB
    int t = threadIdx.x;
    int nwg = gridDim.x;
    int q = nwg >> 3, r = nwg & 7;
    int xcd = blockIdx.x & 7, jj = blockIdx.x >> 3;
    int wg = (xcd < r ? xcd * (q + 1) : r * (q + 1) + (xcd - r) * q) + jj;
    int row0 = (wg / NB) * BM, col0 = (wg % NB) * BN;

    int w = t >> 6, l = t & 63;
    int wr = w >> 1, wc = w & 1;
    f32x4 acc[4][4] = {};

    int srow = w * 8 + (l >> 3);                 // row within 32-row issue chunk
    int scs = (((l & 7) ^ (l >> 3)) * 8);        // source col in shorts (inverse swizzle)
    const unsigned short* ap0 = A + (size_t)min(row0 +  0 + srow, M - 1) * K + scs;
    const unsigned short* ap1 = A + (size_t)min(row0 + 32 + srow, M - 1) * K + scs;
    const unsigned short* ap2 = A + (size_t)min(row0 + 64 + srow, M - 1) * K + scs;
    const unsigned short* ap3 = A + (size_t)min(row0 + 96 + srow, M - 1) * K + scs;
    const unsigned short* bp0 = B + (size_t)(col0 +  0 + srow) * K + scs;
    const unsigned short* bp1 = B + (size_t)(col0 + 32 + srow) * K + scs;
    const unsigned short* bp2 = B + (size_t)(col0 + 64 + srow) * K + scs;
    const unsigned short* bp3 = B + (size_t)(col0 + 96 + srow) * K + scs;
    unsigned short* asd0 = As + 0 * 2048 + w * 512;   // wave-uniform LDS dests
    unsigned short* asd1 = As + 1 * 2048 + w * 512;
    unsigned short* asd2 = As + 2 * 2048 + w * 512;
    unsigned short* asd3 = As + 3 * 2048 + w * 512;
    unsigned short* bsd0 = Bs + 0 * 2048 + w * 512;
    unsigned short* bsd1 = Bs + 1 * 2048 + w * 512;
    unsigned short* bsd2 = Bs + 2 * 2048 + w * 512;
    unsigned short* bsd3 = Bs + 3 * 2048 + w * 512;

    int rr = l & 15;
    int rb = (rr & 7) << 4;          // per-row byte XOR for ds_read
    int kb0 = (l >> 4) << 4;         // 0,16,32,48 byte within K-slice
    const char* Ab = (const char*)As;
    const char* Bb = (const char*)Bs;

#define GLD(src, dst) __builtin_amdgcn_global_load_lds( \
        (const __attribute__((address_space(1))) void*)(src), \
        (__attribute__((address_space(3))) void*)(dst), 16, 0, 0)

    for (int k0 = 0; k0 < K; k0 += BK) {
        GLD(ap0, asd0); GLD(ap1, asd1); GLD(ap2, asd2); GLD(ap3, asd3);
        GLD(bp0, bsd0); GLD(bp1, bsd1); GLD(bp2, bsd2); GLD(bp3, bsd3);
        ap0 += BK; ap1 += BK; ap2 += BK; ap3 += BK;
        bp0 += BK; bp1 += BK; bp2 += BK; bp3 += BK;
        __syncthreads();

#pragma unroll
        for (int ks = 0; ks < 2; ks++) {
            int kb = ((ks << 6) | kb0) ^ rb;
            bf16x8 af[4], bfv[4];
#pragma unroll
            for (int mi = 0; mi < 4; mi++)
                af[mi] = *reinterpret_cast<const bf16x8*>(
                    Ab + (wr * 64 + mi * 16 + rr) * 128 + kb);
#pragma unroll
            for (int ni = 0; ni < 4; ni++)
                bfv[ni] = *reinterpret_cast<const bf16x8*>(
                    Bb + (wc * 64 + ni * 16 + rr) * 128 + kb);
#pragma unroll
            for (int mi = 0; mi < 4; mi++)
#pragma unroll
                for (int ni = 0; ni < 4; ni++)
                    acc[mi][ni] = __builtin_amdgcn_mfma_f32_16x16x32_bf16(
                        af[mi], bfv[ni], acc[mi][ni], 0, 0, 0);
        }
        __syncthreads();
    }
#undef GLD

    // C/D: col = lane&15, row = (lane>>4)*4 + j
    int c_l = l & 15, r_h = (l >> 4) * 4;
#pragma unroll
    for (int mi = 0; mi < 4; mi++)
#pragma unroll
        for (int ni = 0; ni < 4; ni++) {
            int gc = col0 + wc * 64 + ni * 16 + c_l;
#pragma unroll
            for (int j = 0; j < 4; j++) {
                int gr = row0 + wr * 64 + mi * 16 + r_h + j;
                if (gr < M) {
                    float v = acc[mi][ni][j];
                    if (bias) v += bias[gc];
                    if (Cf) Cf[(size_t)gr * N + gc] = v;
                    if (Cb) Cb[(size_t)gr * N + gc] = f2b(v);
                }
            }
        }
}

// ---- a_src/a_dst dots: wave-per-node. Lane l: head l>>4, 16 channels.
// 4-step shuffle reduce over the 16 lanes of each head.
__global__ __launch_bounds__(256) void att_kernel(const unsigned short* __restrict__ hb,
                                                  const float* __restrict__ att_s,
                                                  const float* __restrict__ att_d,
                                                  float* __restrict__ aS, float* __restrict__ aD) {
    int node = blockIdx.x * 4 + (threadIdx.x >> 6);
    int l = threadIdx.x & 63;
    int head = l >> 4, qq = l & 15;
    const unsigned short* hrow = hb + (size_t)node * D1 + head * HID + qq * 16;
    bf16x8 h0 = *reinterpret_cast<const bf16x8*>(hrow);
    bf16x8 h1 = *reinterpret_cast<const bf16x8*>(hrow + 8);
    const float* asp = att_s + head * HID + qq * 16;
    const float* adp = att_d + head * HID + qq * 16;
    float ps = 0.f, pd = 0.f;
#pragma unroll
    for (int c = 0; c < 8; c++) {
        float hv = b2f((unsigned short)h0[c]);
        float hw = b2f((unsigned short)h1[c]);
        ps += hv * asp[c] + hw * asp[8 + c];
        pd += hv * adp[c] + hw * adp[8 + c];
    }
#pragma unroll
    for (int off = 1; off <= 8; off <<= 1) {
        ps += __shfl_xor(ps, off);
        pd += __shfl_xor(pd, off);
    }
    if (qq == 0) {
        aS[node * HEADS + head] = ps;
        aD[node * HEADS + head] = pd;
    }
}

// ---- aggregation: wave-per-node, barrier-free, no LDS.
// Lane l owns channels l*16..l*16+15 (head l>>4); every lane redundantly
// accumulates its head's sum(e) -> no cross-lane reduce needed.
// Edge loop unrolled x4, tail via weight-0 clamp (self-loop => deg>=1).
__global__ __launch_bounds__(256) void agg_kernel(const unsigned short* __restrict__ hb,
                                                  const float* __restrict__ aS,
                                                  const float* __restrict__ aD,
                                                  const int* __restrict__ indptr,
                                                  const int* __restrict__ csr_src,
                                                  const float* __restrict__ bias,
                                                  unsigned short* __restrict__ outb) {
    int node = blockIdx.x * 4 + (threadIdx.x >> 6);
    int l = threadIdx.x & 63;
    int head = l >> 4;
    int beg = indptr[node];
    int deg = indptr[node + 1] - beg;
    float adst = aD[node * HEADS + head];
    const unsigned short* hp = hb + (size_t)l * 16;
    const int* cs = csr_src + beg;
    float acc[16];
#pragma unroll
    for (int c = 0; c < 16; c++) acc[c] = 0.f;
    float esum = 0.f;
    int dm = deg - 1;
    for (int j = 0; j < deg; j += 4) {
        int i0 = j, i1 = min(j + 1, dm), i2 = min(j + 2, dm), i3 = min(j + 3, dm);
        int s0 = cs[i0], s1 = cs[i1], s2 = cs[i2], s3 = cs[i3];
        const unsigned short* r0 = hp + (size_t)s0 * D1;
        const unsigned short* r1 = hp + (size_t)s1 * D1;
        const unsigned short* r2 = hp + (size_t)s2 * D1;
        const unsigned short* r3 = hp + (size_t)s3 * D1;
        bf16x8 r0a = *reinterpret_cast<const bf16x8*>(r0);
        bf16x8 r0b = *reinterpret_cast<const bf16x8*>(r0 + 8);
        bf16x8 r1a = *reinterpret_cast<const bf16x8*>(r1);
        bf16x8 r1b = *reinterpret_cast<const bf16x8*>(r1 + 8);
        bf16x8 r2a = *reinterpret_cast<const bf16x8*>(r2);
        bf16x8 r2b = *reinterpret_cast<const bf16x8*>(r2 + 8);
        bf16x8 r3a = *reinterpret_cast<const bf16x8*>(r3);
        bf16x8 r3b = *reinterpret_cast<const bf16x8*>(r3 + 8);
        float e0 = __expf(lrelu(aS[s0 * HEADS + head] + adst));
        float e1 = (j + 1 <= dm) ? __expf(lrelu(aS[s1 * HEADS + head] + adst)) : 0.f;
        float e2 = (j + 2 <= dm) ? __expf(lrelu(aS[s2 * HEADS + head] + adst)) : 0.f;
        float e3 = (j + 3 <= dm) ? __expf(lrelu(aS[s3 * HEADS + head] + adst)) : 0.f;
        esum += e0 + e1 + e2 + e3;
#pragma unroll
        for (int c = 0; c < 8; c++) {
            acc[c] += e0 * b2f((unsigned short)r0a[c]) + e1 * b2f((unsigned short)r1a[c])
                    + e2 * b2f((unsigned short)r2a[c]) + e3 * b2f((unsigned short)r3a[c]);
            acc[8 + c] += e0 * b2f((unsigned short)r0b[c]) + e1 * b2f((unsigned short)r1b[c])
                        + e2 * b2f((unsigned short)r2b[c]) + e3 * b2f((unsigned short)r3b[c]);
        }
    }
    float inv = 1.f / (esum + 1e-16f);
    const float* bp = bias + l * 16;
    bf16x8 o0, o1;
#pragma unroll
    for (int c = 0; c < 8; c++) {
        o0[c] = (short)f2b(fmaxf(acc[c] * inv + bp[c], 0.f));
        o1[c] = (short)f2b(fmaxf(acc[8 + c] * inv + bp[8 + c], 0.f));
    }
    unsigned short* op = outb + (size_t)node * D1 + l * 16;
    *reinterpret_cast<bf16x8*>(op) = o0;
    *reinterpret_cast<bf16x8*>(op + 8) = o1;
}

extern "C" void kernel_launch(void* const* d_in, const int* in_sizes, int n_in,
                              void* d_out, int out_size, void* d_ws, size_t ws_size,
                              hipStream_t stream) {
    const float* x   = (const float*)d_in[0];
    const void*  ei  = d_in[1];
    const float* W1  = (const float*)d_in[2];
    const float* as1 = (const float*)d_in[3];
    const float* ad1 = (const float*)d_in[4];
    const float* b1  = (const float*)d_in[5];
    const float* W2  = (const float*)d_in[6];
    const float* as2 = (const float*)d_in[7];
    const float* ad2 = (const float*)d_in[8];
    const float* b2  = (const float*)d_in[9];
    const float* fcW = (const float*)d_in[10];
    const float* fcb = (const float*)d_in[11];
    float* out = (float*)d_out;

    char* ws = (char*)d_ws;
    size_t o = 0;
    auto carve = [&](size_t bytes) -> char* {
        char* p = ws + o;
        o = (o + bytes + 255) & ~(size_t)255;
        return p;
    };
    unsigned short* xb   = (unsigned short*)carve((size_t)NN * IN_DIM * 2);
    unsigned short* hb   = (unsigned short*)carve((size_t)NN * D1 * 2);
    unsigned short* x2b  = (unsigned short*)carve((size_t)NN * D1 * 2);
    unsigned short* W1t  = (unsigned short*)carve((size_t)D1 * IN_DIM * 2);
    unsigned short* W2t  = (unsigned short*)carve((size_t)D1 * D1 * 2);
    unsigned short* fcWt = (unsigned short*)carve((size_t)OUT_DIM * D1 * 2);
    float* aS   = (float*)carve((size_t)NN * HEADS * 4);
    float* aD   = (float*)carve((size_t)NN * HEADS * 4);
    int* counts = (int*)carve((size_t)NN * 4);
    int* cursor = (int*)carve((size_t)NN * 4);
    int* indptr = (int*)carve((size_t)(NN + 1) * 4);
    int* csr_src= (int*)carve((size_t)NET * 4);
    int* flag   = (int*)carve(4);
    (void)ws_size; (void)in_sizes; (void)n_in; (void)out_size;

    // CSR build (dtype-agnostic edge loads)
    init_kernel<<<(NN + 255) / 256, 256, 0, stream>>>((const int*)ei, flag, counts, cursor);
    count_kernel<<<(NET + 255) / 256, 256, 0, stream>>>(ei, flag, counts);
    scan_kernel<<<1, 256, 0, stream>>>(counts, indptr);
    fill_kernel<<<(NET + 255) / 256, 256, 0, stream>>>(ei, flag, indptr, cursor, csr_src);

    // fused conversions (cvt + 3 transposes)
    prep_kernel<<<CVT_NB + TP1_NB + TP2_NB + TP3_NB, 256, 0, stream>>>(
        x, xb, W1, W1t, W2, W2t, fcW, fcWt);

    const int MB = (NN + BM - 1) / BM;  // 79
    // layer 1
    gemm128<<<MB * (D1 / BN), 256, 0, stream>>>(xb, W1t, nullptr, nullptr, hb,
                                                NN, D1, IN_DIM, D1 / BN);
    att_kernel<<<NN / 4, 256, 0, stream>>>(hb, as1, ad1, aS, aD);
    agg_kernel<<<NN / 4, 256, 0, stream>>>(hb, aS, aD, indptr, csr_src, b1, x2b);
    // layer 2
    gemm128<<<MB * (D1 / BN), 256, 0, stream>>>(x2b, W2t, nullptr, nullptr, hb,
                                                NN, D1, D1, D1 / BN);
    att_kernel<<<NN / 4, 256, 0, stream>>>(hb, as2, ad2, aS, aD);
    agg_kernel<<<NN / 4, 256, 0, stream>>>(hb, aS, aD, indptr, csr_src, b2, x2b);
    // final fc (bias, f32 out)
    gemm128<<<MB * (OUT_DIM / BN), 256, 0, stream>>>(x2b, fcWt, fcb, out, nullptr,
                                                     NN, OUT_DIM, D1, OUT_DIM / BN);
}